// Round 1
// baseline (165.698 us; speedup 1.0000x reference)
//
#include <hip/hip_runtime.h>
#include <hip/hip_bf16.h>
#include <math.h>

#define COLS 128

// K1: one pass over h_j. Each wave (64 lanes) handles full rows (float2/lane),
// maintains online-softmax state (m, l) and a weighted accumulator (2 floats/lane).
// Block combines its 4 waves via LDS and writes one partial (m_b, l_b, acc_b[128]).
__global__ __launch_bounds__(256, 4) void gat_pass1(
    const float* __restrict__ hj, const float* __restrict__ a,
    float* __restrict__ pacc, float* __restrict__ pm, float* __restrict__ pl,
    int nrows, int nblocks) {
  const int w    = threadIdx.x >> 6;
  const int lane = threadIdx.x & 63;
  const int gw   = blockIdx.x * 4 + w;
  const int total_w = nblocks * 4;

  // a_j = a[128:256]
  const float aj0 = a[COLS + 2 * lane];
  const float aj1 = a[COLS + 2 * lane + 1];

  float m = -INFINITY, l = 0.f, acc0 = 0.f, acc1 = 0.f;

  for (int r = gw; r < nrows; r += total_w) {
    const float2 v = ((const float2*)(hj + (size_t)r * COLS))[lane];
    float p = v.x * aj0 + v.y * aj1;
    // full-wave sum (64 lanes)
    #pragma unroll
    for (int off = 1; off < 64; off <<= 1) p += __shfl_xor(p, off, 64);
    const float mn    = fmaxf(m, p);
    const float alpha = __expf(m - mn);   // m=-inf first iter -> 0
    const float wgt   = __expf(p - mn);
    l    = l * alpha + wgt;
    acc0 = acc0 * alpha + wgt * v.x;
    acc1 = acc1 * alpha + wgt * v.y;
    m = mn;
  }

  __shared__ float sm[4], sl[4], sacc[4][COLS];
  sacc[w][2 * lane]     = acc0;
  sacc[w][2 * lane + 1] = acc1;
  if (lane == 0) { sm[w] = m; sl[w] = l; }
  __syncthreads();

  const int t = threadIdx.x;
  const float Mb = fmaxf(fmaxf(sm[0], sm[1]), fmaxf(sm[2], sm[3]));
  if (t < COLS) {
    float s = 0.f;
    #pragma unroll
    for (int ww = 0; ww < 4; ww++) s += __expf(sm[ww] - Mb) * sacc[ww][t];
    pacc[(size_t)blockIdx.x * COLS + t] = s;
  }
  if (t == 0) {
    float lb = 0.f;
    #pragma unroll
    for (int ww = 0; ww < 4; ww++) lb += __expf(sm[ww] - Mb) * sl[ww];
    pm[blockIdx.x] = Mb;
    pl[blockIdx.x] = lb;
  }
}

// K2: one block per output column. Each block redundantly computes global M and Z
// from the nblocks partials (tiny, L2-resident), then reduces its column and ELUs.
__global__ __launch_bounds__(256) void gat_pass2(
    const float* __restrict__ pacc, const float* __restrict__ pm,
    const float* __restrict__ pl, float* __restrict__ out, int nblocks) {
  const int col = blockIdx.x;
  const int t   = threadIdx.x;
  __shared__ float sM[4], sz[4], sc[4];

  // global max of pm
  float local = -INFINITY;
  for (int b = t; b < nblocks; b += 256) local = fmaxf(local, pm[b]);
  #pragma unroll
  for (int off = 1; off < 64; off <<= 1) local = fmaxf(local, __shfl_xor(local, off, 64));
  if ((t & 63) == 0) sM[t >> 6] = local;
  __syncthreads();
  const float M = fmaxf(fmaxf(sM[0], sM[1]), fmaxf(sM[2], sM[3]));

  // Z and column sum
  float zs = 0.f, cs = 0.f;
  for (int b = t; b < nblocks; b += 256) {
    const float e = __expf(pm[b] - M);
    zs += e * pl[b];
    cs += e * pacc[(size_t)b * COLS + col];
  }
  #pragma unroll
  for (int off = 1; off < 64; off <<= 1) {
    zs += __shfl_xor(zs, off, 64);
    cs += __shfl_xor(cs, off, 64);
  }
  if ((t & 63) == 0) { sz[t >> 6] = zs; sc[t >> 6] = cs; }
  __syncthreads();

  if (t == 0) {
    const float Z = sz[0] + sz[1] + sz[2] + sz[3];
    const float C = sc[0] + sc[1] + sc[2] + sc[3];
    const float h = C / Z;
    out[col] = h > 0.f ? h : expm1f(h);
  }
}

extern "C" void kernel_launch(void* const* d_in, const int* in_sizes, int n_in,
                              void* d_out, int out_size, void* d_ws, size_t ws_size,
                              hipStream_t stream) {
  const float* hj = (const float*)d_in[1];
  const float* a  = (const float*)d_in[2];
  float* out = (float*)d_out;

  const int nrows = in_sizes[1] / COLS;

  // workspace layout: pacc[nblocks*128] | pm[nblocks] | pl[nblocks]
  const size_t per_block = (COLS + 2) * sizeof(float);
  int nblocks = 1024;
  if (ws_size < (size_t)nblocks * per_block) {
    nblocks = (int)(ws_size / per_block);
    if (nblocks > 256) nblocks &= ~63;  // keep it tidy
    if (nblocks < 1) nblocks = 1;
  }
  float* pacc = (float*)d_ws;
  float* pm   = pacc + (size_t)nblocks * COLS;
  float* pl   = pm + nblocks;

  gat_pass1<<<nblocks, 256, 0, stream>>>(hj, a, pacc, pm, pl, nrows, nblocks);
  gat_pass2<<<COLS, 256, 0, stream>>>(pacc, pm, pl, out, nblocks);
}

// Round 2
// 155.899 us; speedup vs baseline: 1.0629x; 1.0629x over previous
//
#include <hip/hip_runtime.h>
#include <math.h>

#define COLS 128

// K1: single pass over h_j (102.4 MB read once). 8 "units" per block = half-waves
// of 32 lanes; each unit owns rows unit, unit+NU, ... Lane sub (0..31) holds
// columns 4*sub..4*sub+3 via float4. Online softmax with branchy rare-rescale.
__global__ __launch_bounds__(256) void gat_pass1(
    const float* __restrict__ hj, const float* __restrict__ a,
    float* __restrict__ pacc, float* __restrict__ pm, float* __restrict__ pl,
    int nrows, int nunits) {
  const int t    = threadIdx.x;
  const int wave = t >> 6;
  const int lane = t & 63;
  const int half = lane >> 5;
  const int sub  = lane & 31;
  const int uib  = wave * 2 + half;          // unit in block, 0..7
  const int unit = blockIdx.x * 8 + uib;

  const float4 aj = ((const float4*)(a + COLS))[sub];

  float m = -INFINITY, l = 0.f;
  float ax = 0.f, ay = 0.f, az = 0.f, aw = 0.f;

  const int stride = nunits;
  int r = unit;

  for (; r + stride < nrows; r += 2 * stride) {
    const float4 v0 = ((const float4*)(hj + (size_t)r * COLS))[sub];
    const float4 v1 = ((const float4*)(hj + (size_t)(r + stride) * COLS))[sub];

    float p0 = v0.x * aj.x + v0.y * aj.y + v0.z * aj.z + v0.w * aj.w;
    #pragma unroll
    for (int off = 1; off <= 16; off <<= 1) p0 += __shfl_xor(p0, off, 64);
    if (p0 <= m) {
      const float w = __expf(p0 - m);
      l += w; ax += w * v0.x; ay += w * v0.y; az += w * v0.z; aw += w * v0.w;
    } else {
      const float alpha = __expf(m - p0);   // exp(-inf)=0 on first hit
      l = l * alpha + 1.f;
      ax = ax * alpha + v0.x; ay = ay * alpha + v0.y;
      az = az * alpha + v0.z; aw = aw * alpha + v0.w;
      m = p0;
    }

    float p1 = v1.x * aj.x + v1.y * aj.y + v1.z * aj.z + v1.w * aj.w;
    #pragma unroll
    for (int off = 1; off <= 16; off <<= 1) p1 += __shfl_xor(p1, off, 64);
    if (p1 <= m) {
      const float w = __expf(p1 - m);
      l += w; ax += w * v1.x; ay += w * v1.y; az += w * v1.z; aw += w * v1.w;
    } else {
      const float alpha = __expf(m - p1);
      l = l * alpha + 1.f;
      ax = ax * alpha + v1.x; ay = ay * alpha + v1.y;
      az = az * alpha + v1.z; aw = aw * alpha + v1.w;
      m = p1;
    }
  }
  for (; r < nrows; r += stride) {
    const float4 v0 = ((const float4*)(hj + (size_t)r * COLS))[sub];
    float p0 = v0.x * aj.x + v0.y * aj.y + v0.z * aj.z + v0.w * aj.w;
    #pragma unroll
    for (int off = 1; off <= 16; off <<= 1) p0 += __shfl_xor(p0, off, 64);
    if (p0 <= m) {
      const float w = __expf(p0 - m);
      l += w; ax += w * v0.x; ay += w * v0.y; az += w * v0.z; aw += w * v0.w;
    } else {
      const float alpha = __expf(m - p0);
      l = l * alpha + 1.f;
      ax = ax * alpha + v0.x; ay = ay * alpha + v0.y;
      az = az * alpha + v0.z; aw = aw * alpha + v0.w;
      m = p0;
    }
  }

  // Block combine: 8 units -> one partial (Mb, lb, accb[128])
  __shared__ float sm[8], sl[8], se[8], sMb;
  __shared__ float sacc[8][COLS];
  ((float4*)sacc[uib])[sub] = make_float4(ax, ay, az, aw);
  if (sub == 0) { sm[uib] = m; sl[uib] = l; }
  __syncthreads();

  if (t < 8) {
    float Mb = sm[0];
    #pragma unroll
    for (int u = 1; u < 8; u++) Mb = fmaxf(Mb, sm[u]);
    se[t] = __expf(sm[t] - Mb);
    if (t == 0) sMb = Mb;
  }
  __syncthreads();

  if (t < COLS) {
    float s = 0.f;
    #pragma unroll
    for (int u = 0; u < 8; u++) s += se[u] * sacc[u][t];
    pacc[(size_t)blockIdx.x * COLS + t] = s;
  }
  if (t == 0) {
    float lb = 0.f;
    #pragma unroll
    for (int u = 0; u < 8; u++) lb += se[u] * sl[u];
    pm[blockIdx.x] = sMb;
    pl[blockIdx.x] = lb;
  }
}

// K2: one block per output column; redundant global (M, Z) from the tiny
// L2-resident partials, then column reduce + ELU.
__global__ __launch_bounds__(256) void gat_pass2(
    const float* __restrict__ pacc, const float* __restrict__ pm,
    const float* __restrict__ pl, float* __restrict__ out, int nblocks) {
  const int col = blockIdx.x;
  const int t   = threadIdx.x;
  __shared__ float sM[4], sz[4], sc[4];

  float local = -INFINITY;
  for (int b = t; b < nblocks; b += 256) local = fmaxf(local, pm[b]);
  #pragma unroll
  for (int off = 1; off < 64; off <<= 1) local = fmaxf(local, __shfl_xor(local, off, 64));
  if ((t & 63) == 0) sM[t >> 6] = local;
  __syncthreads();
  const float M = fmaxf(fmaxf(sM[0], sM[1]), fmaxf(sM[2], sM[3]));

  float zs = 0.f, cs = 0.f;
  for (int b = t; b < nblocks; b += 256) {
    const float e = __expf(pm[b] - M);
    zs += e * pl[b];
    cs += e * pacc[(size_t)b * COLS + col];
  }
  #pragma unroll
  for (int off = 1; off < 64; off <<= 1) {
    zs += __shfl_xor(zs, off, 64);
    cs += __shfl_xor(cs, off, 64);
  }
  if ((t & 63) == 0) { sz[t >> 6] = zs; sc[t >> 6] = cs; }
  __syncthreads();

  if (t == 0) {
    const float Z = sz[0] + sz[1] + sz[2] + sz[3];
    const float C = sc[0] + sc[1] + sc[2] + sc[3];
    const float h = C / Z;
    out[col] = h > 0.f ? h : expm1f(h);
  }
}

extern "C" void kernel_launch(void* const* d_in, const int* in_sizes, int n_in,
                              void* d_out, int out_size, void* d_ws, size_t ws_size,
                              hipStream_t stream) {
  const float* hj = (const float*)d_in[1];
  const float* a  = (const float*)d_in[2];
  float* out = (float*)d_out;

  const int nrows = in_sizes[1] / COLS;

  int nblocks = 2048;  // 8 blocks/CU -> 32 waves/CU
  const size_t per_block = (COLS + 2) * sizeof(float);
  if (ws_size < (size_t)nblocks * per_block) {
    nblocks = (int)(ws_size / per_block);
    if (nblocks > 64) nblocks &= ~63;
    if (nblocks < 1) nblocks = 1;
  }
  const int nunits = nblocks * 8;

  float* pacc = (float*)d_ws;
  float* pm   = pacc + (size_t)nblocks * COLS;
  float* pl   = pm + nblocks;

  gat_pass1<<<nblocks, 256, 0, stream>>>(hj, a, pacc, pm, pl, nrows, nunits);
  gat_pass2<<<COLS, 256, 0, stream>>>(pacc, pm, pl, out, nblocks);
}